// Round 5
// baseline (876.013 us; speedup 1.0000x reference)
//
#include <hip/hip_runtime.h>

// WindowAttention: B=256 windows, N=256 tokens, C=384, 12 heads, d=32.
//   K0: cast weights -> bf16
//   K1: transpose-cast x (B,C,N) f32 -> xf (B*N, C) bf16   [R2-proven]
//   K2: MEGA — one block per window, 512 thr, loop h=0..11:
//       qkv MFMA32 GEMM (A=wq, B=xf direct) + bias + l2norm -> q/k/v LDS (R4 frag layouts)
//       -> R4 attention (MFMA32 S^T, register P-exchange, MFMA32 O^T)
//       -> proj split-K per head into 192 f32 regs/lane (O->B-frag via xor-32 exchange)
//       final: +proj_b, f32 stores out (B,C,N).
// 32x32x16 layouts: A/B: row=lane&31, k=(lane>>5)*8+j ; D: col=lane&31, row=(reg&3)+8*(reg>>2)+4*(lane>>5)
// Softmax: |logit| <= 0.178 -> no max-subtract; clip(1e-6,1) provably no-op.
// All LDS RAW: scalar/b64 writes -> __syncthreads -> b128 reads (R3's race pattern excluded).

#define DIM 384
#define NT 256
#define NH 12
#define SCALE 0.17677669529663687f

typedef __bf16 bf16;
typedef __bf16 bf16x4 __attribute__((ext_vector_type(4)));
typedef __bf16 bf16x8 __attribute__((ext_vector_type(8)));
typedef float f32x4 __attribute__((ext_vector_type(4)));
typedef float f32x16 __attribute__((ext_vector_type(16)));

#define MFMA32(a, b, c) __builtin_amdgcn_mfma_f32_32x32x16_bf16(a, b, c, 0, 0, 0)

union U2H4 { bf16x4 h; uint2 u; };
union U4H8 { bf16x8 h; uint4 u; };

// ---------------- K0: cast weights ----------------
__global__ void k_cast_w(const float* __restrict__ qkv_w, const float* __restrict__ proj_w,
                         bf16* __restrict__ wq, bf16* __restrict__ wp) {
    int i = blockIdx.x * 256 + threadIdx.x;
    if (i < 3 * DIM * DIM) wq[i] = (bf16)qkv_w[i];
    if (i < DIM * DIM)     wp[i] = (bf16)proj_w[i];
}

// ---------------- K1: x (B,C,N) f32 -> xf (B*N, C) bf16 [R2-proven] ----------------
__global__ void k_transpose_cast(const float* __restrict__ x, bf16* __restrict__ xt) {
    __shared__ float tile[64][65];
    const int b = blockIdx.z, c0 = blockIdx.y * 64, n0 = blockIdx.x * 64;
    const int tx = threadIdx.x & 63, ty = threadIdx.x >> 6;  // ty 0..3
    const float* xp = x + (size_t)b * DIM * NT;
#pragma unroll
    for (int i = 0; i < 16; ++i) {
        int c = ty + i * 4;
        tile[c][tx] = xp[(size_t)(c0 + c) * NT + n0 + tx];
    }
    __syncthreads();
    bf16* op = xt + (size_t)b * NT * DIM;
#pragma unroll
    for (int i = 0; i < 16; ++i) {
        int n = ty + i * 4;
        op[(size_t)(n0 + n) * DIM + c0 + tx] = (bf16)tile[tx][n];
    }
}

// ---------------- K2: MEGA — one block per window ----------------
__launch_bounds__(512, 1)
__global__ void k_mega(const bf16* __restrict__ xf, const bf16* __restrict__ wq,
                       const float* __restrict__ qkv_b, const bf16* __restrict__ wp,
                       const float* __restrict__ proj_b, float* __restrict__ out) {
    __shared__ bf16 qfr[2][2][NT][8];   // q[tok][d]: [d>>4][(d>>3)&1][tok][d&7]  16,384 B
    __shared__ bf16 kfr[2][2][NT][8];   // 16,384 B
    __shared__ bf16 vfr[32][32][8];     // V[tok][d] at [tok>>3][d][tok&7]        16,384 B
    __shared__ float bias_s[3 * DIM];   // 4,608 B
    __shared__ float pbias_s[DIM];      // 1,536 B   -> total 55,296 B

    const int b = blockIdx.x;
    const int tid = threadIdx.x, lane = tid & 63, w = tid >> 6;   // 8 waves
    const int l31 = lane & 31, half = lane >> 5;
    const bool hi_half = (half != 0);
    const f32x16 z16 = {0.f,0.f,0.f,0.f,0.f,0.f,0.f,0.f,0.f,0.f,0.f,0.f,0.f,0.f,0.f,0.f};

    for (int i = tid; i < 3 * DIM; i += 512) bias_s[i] = qkv_b[i];
    if (tid < DIM) pbias_s[tid] = proj_b[tid];
    __syncthreads();

    const int tok = w * 32 + l31;  // lane's token (GEMM B col / query)
    const bf16* xrow = xf + ((size_t)(b * NT) + tok) * DIM + half * 8;

    f32x16 pacc[12];
#pragma unroll
    for (int ct = 0; ct < 12; ++ct) pacc[ct] = z16;

#pragma unroll 1
    for (int h = 0; h < NH; ++h) {
        // ---- qkv GEMM: 96 out-cols (q|k|v of head h) x 32 toks, K=384
        f32x16 qacc[3] = {z16, z16, z16};
        const bf16* w0 = wq + ((size_t)(0 * DIM + h * 32 + l31)) * DIM + half * 8;
        const bf16* w1 = wq + ((size_t)(1 * DIM + h * 32 + l31)) * DIM + half * 8;
        const bf16* w2 = wq + ((size_t)(2 * DIM + h * 32 + l31)) * DIM + half * 8;
#pragma unroll 4
        for (int kc = 0; kc < 24; ++kc) {
            bf16x8 xv = *(const bf16x8*)(xrow + kc * 16);
            qacc[0] = MFMA32(*(const bf16x8*)(w0 + kc * 16), xv, qacc[0]);
            qacc[1] = MFMA32(*(const bf16x8*)(w1 + kc * 16), xv, qacc[1]);
            qacc[2] = MFMA32(*(const bf16x8*)(w2 + kc * 16), xv, qacc[2]);
        }

        // ---- epilogue: +bias, l2norm(q,k), write LDS frag layouts
        float vq[16], vk[16], vv[16];
        float sq = 0.f, sk = 0.f;
#pragma unroll
        for (int r = 0; r < 16; ++r) {
            int m = (r & 3) + 8 * (r >> 2) + 4 * half;  // d index
            vq[r] = qacc[0][r] + bias_s[h * 32 + m];
            vk[r] = qacc[1][r] + bias_s[DIM + h * 32 + m];
            vv[r] = qacc[2][r] + bias_s[2 * DIM + h * 32 + m];
            sq += vq[r] * vq[r];
            sk += vk[r] * vk[r];
        }
        sq += __shfl_xor(sq, 32);
        sk += __shfl_xor(sk, 32);
        float iq = 1.f / fmaxf(sqrtf(sq), 1e-12f);
        float ik = 1.f / fmaxf(sqrtf(sk), 1e-12f);
#pragma unroll
        for (int g = 0; g < 4; ++g) {
            // reg quad g covers d = 8g + 4*half + r
            bf16x4 q4 = {(bf16)(vq[g*4+0]*iq), (bf16)(vq[g*4+1]*iq), (bf16)(vq[g*4+2]*iq), (bf16)(vq[g*4+3]*iq)};
            bf16x4 k4 = {(bf16)(vk[g*4+0]*ik), (bf16)(vk[g*4+1]*ik), (bf16)(vk[g*4+2]*ik), (bf16)(vk[g*4+3]*ik)};
            *(bf16x4*)&qfr[g >> 1][g & 1][tok][4 * half] = q4;
            *(bf16x4*)&kfr[g >> 1][g & 1][tok][4 * half] = k4;
#pragma unroll
            for (int r = 0; r < 4; ++r)
                vfr[tok >> 3][8 * g + 4 * half + r][tok & 7] = (bf16)vv[g * 4 + r];
        }
        __syncthreads();

        // ---- attention (R4-proven structure), queries = this wave's 32 toks
        bf16x8 qf0 = *(const bf16x8*)&qfr[0][half][tok][0];
        bf16x8 qf1 = *(const bf16x8*)&qfr[1][half][tok][0];
        f32x16 ot = z16;
        float dsum = 0.f;
#pragma unroll 1
        for (int kt = 0; kt < 8; ++kt) {
            bf16x8 ka0 = *(const bf16x8*)&kfr[0][half][kt * 32 + l31][0];
            bf16x8 ka1 = *(const bf16x8*)&kfr[1][half][kt * 32 + l31][0];
            f32x16 s = MFMA32(ka0, qf0, z16);
            s = MFMA32(ka1, qf1, s);
            U2H4 pk[4];  // reg g*4+r = P^T[key = r+8g+4half][query l31]
#pragma unroll
            for (int g2 = 0; g2 < 4; ++g2)
#pragma unroll
                for (int r = 0; r < 4; ++r) {
                    float p = __expf(s[g2 * 4 + r] * SCALE);  // |logit|<=0.178
                    dsum += p;
                    pk[g2].h[r] = (bf16)p;
                }
#pragma unroll
            for (int c16 = 0; c16 < 2; ++c16) {
                uint2 A  = hi_half ? pk[c16 * 2 + 1].u : pk[c16 * 2].u;
                uint2 Bv = hi_half ? pk[c16 * 2].u     : pk[c16 * 2 + 1].u;
                uint2 Bx = {(unsigned)__shfl_xor((int)Bv.x, 32), (unsigned)__shfl_xor((int)Bv.y, 32)};
                uint2 lo = hi_half ? Bx : A;
                uint2 hi = hi_half ? A : Bx;
                U4H8 pf; pf.u = (uint4){lo.x, lo.y, hi.x, hi.y};
                bf16x8 va = *(const bf16x8*)&vfr[kt * 4 + c16 * 2 + half][l31][0];
                ot = MFMA32(va, pf.h, ot);
            }
        }
        dsum += __shfl_xor(dsum, 32);
        float inv = 1.f / dsum;

        // O^T regs -> proj B-frags via the same xor-32 exchange
        U2H4 od[4];  // od[g].h[r] = O[query l31][d = r+8g+4half] * inv
#pragma unroll
        for (int g = 0; g < 4; ++g)
#pragma unroll
            for (int r = 0; r < 4; ++r)
                od[g].h[r] = (bf16)(ot[g * 4 + r] * inv);
        bf16x8 ofr[2];
#pragma unroll
        for (int c16 = 0; c16 < 2; ++c16) {
            uint2 A  = hi_half ? od[c16 * 2 + 1].u : od[c16 * 2].u;
            uint2 Bv = hi_half ? od[c16 * 2].u     : od[c16 * 2 + 1].u;
            uint2 Bx = {(unsigned)__shfl_xor((int)Bv.x, 32), (unsigned)__shfl_xor((int)Bv.y, 32)};
            uint2 lo = hi_half ? Bx : A;
            uint2 hi = hi_half ? A : Bx;
            U4H8 pf; pf.u = (uint4){lo.x, lo.y, hi.x, hi.y};
            ofr[c16] = pf.h;  // B-frag: O[k = d = c16*16+half*8+j][n = tok l31]
        }

        // ---- proj split-K: pacc[ct] += Wp[ct*32+l31][h*32 + k] * O
#pragma unroll 2
        for (int ct = 0; ct < 12; ++ct) {
            const bf16* wr = wp + ((size_t)(ct * 32 + l31)) * DIM + h * 32 + half * 8;
            pacc[ct] = MFMA32(*(const bf16x8*)(wr),      ofr[0], pacc[ct]);
            pacc[ct] = MFMA32(*(const bf16x8*)(wr + 16), ofr[1], pacc[ct]);
        }
        __syncthreads();  // protect q/k/v LDS rewrite next head
    }

    // ---- final store: out[b][c][tok] f32, 128B dense per instruction
    float* op = out + (size_t)b * DIM * NT;
#pragma unroll
    for (int ct = 0; ct < 12; ++ct)
#pragma unroll
        for (int r = 0; r < 16; ++r) {
            int c = ct * 32 + (r & 3) + 8 * (r >> 2) + 4 * half;
            op[(size_t)c * NT + w * 32 + l31] = pacc[ct][r] + pbias_s[c];
        }
}

extern "C" void kernel_launch(void* const* d_in, const int* in_sizes, int n_in,
                              void* d_out, int out_size, void* d_ws, size_t ws_size,
                              hipStream_t stream) {
    const float* x      = (const float*)d_in[0];
    const float* qkv_w  = (const float*)d_in[1];
    const float* qkv_b  = (const float*)d_in[2];
    const float* proj_w = (const float*)d_in[3];
    const float* proj_b = (const float*)d_in[4];
    float* out = (float*)d_out;

    char* ws = (char*)d_ws;
    bf16* xf = (bf16*)ws;                    // 256*256*384*2 = 50,331,648 B
    bf16* wq = (bf16*)(ws + 50331648);       // 884,736 B
    bf16* wp = (bf16*)(ws + 51216384);       // 294,912 B   -> total 51,511,296 B

    k_cast_w<<<dim3(1728), dim3(256), 0, stream>>>(qkv_w, proj_w, wq, wp);
    k_transpose_cast<<<dim3(4, 6, 256), dim3(256), 0, stream>>>(x, xf);
    k_mega<<<dim3(256), dim3(512), 0, stream>>>(xf, wq, qkv_b, wp, proj_b, out);
}